// Round 2
// baseline (147.149 us; speedup 1.0000x reference)
//
#include <hip/hip_runtime.h>
#include <hip/hip_bf16.h>
#include <cmath>

#define BB 4
#define NN 2048
#define DIN 128
#define HH 4
#define HD 32
#define KSEL 204            // int(0.1 * 2048)
#define BH (BB*HH)
#define KPAD 256            // K padded to 8 MFMA steps of 32
#define KST 264             // PSb row stride (shorts): 132 words -> 2-way banks (free)

typedef __attribute__((ext_vector_type(8))) short short8;
typedef __attribute__((ext_vector_type(4))) short short4v;
typedef __attribute__((ext_vector_type(4))) float float4v;

static __device__ inline short f2bf(float x) {
    __hip_bfloat16 b = __float2bfloat16(x);   // RNE
    return __builtin_bit_cast(short, b);
}

// ---------------------------------------------------------------------------
// K1: s_i = h.(W@a1), s_j = h.(W@a2) (f32-exact). 128 blocks for parallelism.
// (round-0 version, measured-good)
__global__ __launch_bounds__(256) void s_kernel(const float* __restrict__ h,
                                                const float* __restrict__ W,
                                                const float* __restrict__ a,
                                                float* __restrict__ si, float* __restrict__ sj) {
    int bh = blockIdx.x >> 3, chunk = blockIdx.x & 7;
    int b = bh >> 2, hh = bh & 3;
    __shared__ float w1[128], w2[128];
    int t = threadIdx.x;
    {   // wa = W[hh] @ a-halves, computed in-block
        int f = t & 127, half = t >> 7;
        const float* Wp = W + (size_t)hh * (DIN * HD) + f * HD;
        const float* ap = a + hh * 64 + half * 32;
        float acc = 0.f;
#pragma unroll
        for (int d = 0; d < 32; ++d) acc += Wp[d] * ap[d];
        if (half == 0) w1[f] = acc; else w2[f] = acc;
    }
    __syncthreads();
    int n = chunk * 256 + t;
    const float4* hr = (const float4*)(h + ((size_t)b * NN + n) * DIN);
    float s1 = 0.f, s2 = 0.f;
#pragma unroll 8
    for (int q = 0; q < 32; ++q) {
        float4 x = hr[q];
        s1 += x.x * w1[q*4] + x.y * w1[q*4+1] + x.z * w1[q*4+2] + x.w * w1[q*4+3];
        s2 += x.x * w2[q*4] + x.y * w2[q*4+1] + x.z * w2[q*4+2] + x.w * w2[q*4+3];
    }
    int o = bh * NN + n;
    si[o] = s1; sj[o] = s2;
}

// ---------------------------------------------------------------------------
// K2: select per (b,h), 1024 threads (16 waves):
//  radix-select top-KSEL (register keys, parallel suffix-scan), ordered
//  compaction, then Whsel[bh][d][jj] = bf16( h[sel jj] @ W[hh] ) via MFMA
//  (Wh is ONLY ever needed for the 204 selected rows -> no full wh pass).
__global__ __launch_bounds__(1024) void select_kernel(
        const float* __restrict__ h, const float* __restrict__ W,
        const float* __restrict__ sj,
        int* __restrict__ idxsel, float* __restrict__ sjsel,
        float* __restrict__ sjmax, short* __restrict__ Whsel) {
    int bh = blockIdx.x;
    int b = bh >> 2, hh = bh & 3;
    int t = threadIdx.x, lane = t & 63, w = t >> 6;
    __shared__ float sv[NN];
    __shared__ short WT[32][136];            // WT[d][k] = bf16(W[hh][k][d])
    __shared__ int hist16[16][256];
    __shared__ int binInfo[2];               // [0]=Bsel, [1]=cum_before
    __shared__ int wtot[4];
    __shared__ int wtotg[16], wtote[16], woffg[16], woffe[16];
    __shared__ float wmax[16];
    __shared__ int idxLDS[KSEL];

    for (int e = t; e < 32 * 128; e += 1024) {
        int n = e >> 7, k = e & 127;
        WT[n][k] = f2bf(W[(size_t)hh * (DIN * HD) + k * HD + n]);
    }

    // coalesced sj load; keys in registers
    const float* s = sj + (size_t)bh * NN;
    int j0 = t * 2;
    float2 xx = *(const float2*)(s + j0);
    sv[j0] = xx.x; sv[j0 + 1] = xx.y;
    unsigned u0 = __builtin_bit_cast(unsigned, xx.x);
    unsigned u1 = __builtin_bit_cast(unsigned, xx.y);
    u0 = (u0 & 0x80000000u) ? ~u0 : (u0 | 0x80000000u);
    u1 = (u1 & 0x80000000u) ? ~u1 : (u1 | 0x80000000u);
    float lmax = fmaxf(xx.x, xx.y);
#pragma unroll
    for (int off = 32; off >= 1; off >>= 1) lmax = fmaxf(lmax, __shfl_xor(lmax, off));
    if (lane == 0) wmax[w] = lmax;
    __syncthreads();
    if (t == 0) {
        float m = wmax[0];
#pragma unroll
        for (int i = 1; i < 16; ++i) m = fmaxf(m, wmax[i]);
        sjmax[bh] = m;
    }

    // radix: 4-pass byte histogram, parallel suffix-scan threshold search
    unsigned prefix = 0;
    int need = KSEL;
#pragma unroll
    for (int shift = 24; shift >= 0; shift -= 8) {
        ((int*)hist16)[t] = 0; ((int*)hist16)[t + 1024] = 0;
        ((int*)hist16)[t + 2048] = 0; ((int*)hist16)[t + 3072] = 0;
        __syncthreads();
        unsigned hmask = (shift < 24) ? (0xFFFFFFFFu << (shift + 8)) : 0u;
        if (((u0 ^ prefix) & hmask) == 0) atomicAdd(&hist16[w][(u0 >> shift) & 255], 1);
        if (((u1 ^ prefix) & hmask) == 0) atomicAdd(&hist16[w][(u1 >> shift) & 255], 1);
        __syncthreads();
        int sc = 0, hv = 0, bb = 0;
        if (t < 256) {                 // waves 0..3
            bb = 255 - t;
            hv = 0;
#pragma unroll
            for (int i = 0; i < 16; ++i) hv += hist16[i][bb];
            sc = hv;
#pragma unroll
            for (int off = 1; off < 64; off <<= 1) {
                int u = __shfl_up(sc, off);
                if (lane >= off) sc += u;
            }
            if (lane == 63) wtot[w] = sc;
        }
        __syncthreads();
        if (t < 256) {
            int woffset = 0;
#pragma unroll
            for (int i = 0; i < 4; ++i) woffset += (i < w) ? wtot[i] : 0;
            int incl = sc + woffset;
            int excl = incl - hv;
            if (incl >= need && excl < need) {   // unique thread
                binInfo[0] = bb;
                binInfo[1] = excl;
            }
        }
        __syncthreads();
        prefix |= ((unsigned)binInfo[0]) << shift;
        need -= binInfo[1];
        __syncthreads();
    }
    unsigned T = prefix;
    int n_gt = KSEL - need;        // count of keys strictly > T

    // ordered compaction (thread t owns j0, j0+1)
    int cg = (u0 > T ? 1 : 0) + (u1 > T ? 1 : 0);
    int ce = (u0 == T ? 1 : 0) + (u1 == T ? 1 : 0);
    int sg = cg, se = ce;
#pragma unroll
    for (int off = 1; off < 64; off <<= 1) {
        int ug = __shfl_up(sg, off), ue = __shfl_up(se, off);
        if (lane >= off) { sg += ug; se += ue; }
    }
    if (lane == 63) { wtotg[w] = sg; wtote[w] = se; }
    __syncthreads();
    if (t == 0) {
        int rg = 0, re = 0;
#pragma unroll
        for (int i = 0; i < 16; ++i) {
            woffg[i] = rg; rg += wtotg[i];
            woffe[i] = re; re += wtote[i];
        }
    }
    __syncthreads();
    int pg = woffg[w] + sg - cg;
    int te = woffe[w] + se - ce;
    {
        unsigned kk[2] = {u0, u1};
#pragma unroll
        for (int r = 0; r < 2; ++r) {
            int j = j0 + r;
            if (kk[r] > T) {
                idxsel[bh * KSEL + pg] = j;
                sjsel[bh * KSEL + pg] = sv[j];
                idxLDS[pg] = j;
                pg++;
            } else if (kk[r] == T) {
                if (te < need) {
                    int pos = n_gt + te;
                    idxsel[bh * KSEL + pos] = j;
                    sjsel[bh * KSEL + pos] = sv[j];
                    idxLDS[pos] = j;
                }
                te++;
            }
        }
    }
    __syncthreads();

    // Phase D: Whsel[bh][d][jj] = bf16( h[idxLDS[jj]] @ W[hh] ), tail zero.
    {
        int mr = lane & 15, quad = lane >> 4;
        int jjp = w * 16 + mr;
        bool valid = jjp < KSEL;
        const float* hrow = h + ((size_t)b * NN + (valid ? idxLDS[jjp] : 0)) * DIN + quad * 8;
        float4v acc0 = {0.f, 0.f, 0.f, 0.f};
        float4v acc1 = {0.f, 0.f, 0.f, 0.f};
#pragma unroll
        for (int ks = 0; ks < 4; ++ks) {
            short8 afr;
            if (valid) {
                float4 xa = *(const float4*)(hrow + ks * 32);
                float4 xb = *(const float4*)(hrow + ks * 32 + 4);
                afr[0] = f2bf(xa.x); afr[1] = f2bf(xa.y); afr[2] = f2bf(xa.z); afr[3] = f2bf(xa.w);
                afr[4] = f2bf(xb.x); afr[5] = f2bf(xb.y); afr[6] = f2bf(xb.z); afr[7] = f2bf(xb.w);
            } else {
                afr = (short8){0, 0, 0, 0, 0, 0, 0, 0};
            }
            short8 b0 = *(const short8*)&WT[mr][ks * 32 + quad * 8];
            short8 b1 = *(const short8*)&WT[16 + mr][ks * 32 + quad * 8];
            acc0 = __builtin_amdgcn_mfma_f32_16x16x32_bf16(afr, b0, acc0, 0, 0, 0);
            acc1 = __builtin_amdgcn_mfma_f32_16x16x32_bf16(afr, b1, acc1, 0, 0, 0);
        }
        short4v o0, o1;
#pragma unroll
        for (int r = 0; r < 4; ++r) { o0[r] = f2bf(acc0[r]); o1[r] = f2bf(acc1[r]); }
        size_t base = (size_t)bh * HD * KPAD;
        int jjs = w * 16 + quad * 4;
        *(short4v*)&Whsel[base + (size_t)mr * KPAD + jjs] = o0;
        *(short4v*)&Whsel[base + (size_t)(16 + mr) * KPAD + jjs] = o1;
    }
}

// ---------------------------------------------------------------------------
// K3: FUSED attention. Block = (b, 16 rows, 4 heads-as-waves), grid 512.
// Round-0 structure (4-row stages, single 32 KB adjbuf, 7 barriers, 8
// float4/thread per stage) + ONE change: stage-(s+1) global loads are
// ISSUED before the stage-s compute (T14 issue-early), so the write phase
// between the two barriers no longer exposes HBM latency. si preloaded per
// wave and broadcast via shfl.
__global__ __launch_bounds__(256) void attn2_kernel(
        const float* __restrict__ adj, const float* __restrict__ si,
        const int* __restrict__ idxsel, const float* __restrict__ sjsel,
        const float* __restrict__ sjmax, const short* __restrict__ Whsel,
        float* __restrict__ out) {
    int b = blockIdx.x >> 7;        // 4
    int tile = blockIdx.x & 127;    // 128 tiles of 16 rows
    __shared__ float adjbuf[4][NN];          // 32 KB
    __shared__ short PSb[HH][16][KST];       // 33 KB, per-head private
    __shared__ int   idxS[HH][KPAD];         // 4 KB
    __shared__ float sjS[HH][KPAD];          // 4 KB
    __shared__ float invZS[HH][16];
    __shared__ float smaxS[HH];
    int t = threadIdx.x, w = t >> 6, lane = t & 63;
    int mr = lane & 15, quad = lane >> 4;

    int i0 = tile * 16;
    const float* adjb = adj + (size_t)b * NN * NN + (size_t)i0 * NN;

    // issue stage-0 adj loads FIRST (8 dwordx4 in flight / thread)
    float4 pre[8];
    {
        const float4* src = (const float4*)adjb;
#pragma unroll
        for (int q = 0; q < 8; ++q) pre[q] = src[q * 256 + t];
    }

    // per-head tables (overlap the in-flight adj loads)
    for (int e = t; e < HH * KPAD; e += 256) {
        int hh = e >> 8, jj = e & 255;
        bool v = jj < KSEL;
        idxS[hh][jj] = v ? idxsel[(b * HH + hh) * KSEL + jj] : 0;
        sjS[hh][jj]  = v ? sjsel[(b * HH + hh) * KSEL + jj] : -1e30f;
    }
    if (t < HH) smaxS[t] = sjmax[b * HH + t];

    // B-fragments for head w (registers, reused all block)
    short8 bfr[2][8];
    {
        const short* wp = Whsel + (size_t)((b * HH + w) * HD) * KPAD;
#pragma unroll
        for (int ni = 0; ni < 2; ++ni)
#pragma unroll
            for (int ks = 0; ks < 8; ++ks)
                bfr[ni][ks] = *(const short8*)(wp + (size_t)(ni * 16 + mr) * KPAD + ks * 32 + quad * 8);
    }

    // si preload: lane l (<16) holds row i0+l of this wave's head
    int bh = b * HH + w;
    float sivAll = (lane < 16) ? si[(size_t)bh * NN + i0 + lane] : 0.f;

    // write stage 0 to LDS
    {
        float4* dst = (float4*)adjbuf;
#pragma unroll
        for (int q = 0; q < 8; ++q) dst[q * 256 + t] = pre[q];
    }
    __syncthreads();

    float smax = smaxS[w];
    for (int s = 0; s < 4; ++s) {
        // issue next-stage loads EARLY: latency hides under the compute below
        if (s < 3) {
            const float4* src = (const float4*)(adjb + (size_t)(s + 1) * 4 * NN);
#pragma unroll
            for (int q = 0; q < 8; ++q) pre[q] = src[q * 256 + t];
        }
#pragma unroll
        for (int r = 0; r < 4; ++r) {
            int i_loc = s * 4 + r;
            float siv = __shfl(sivAll, i_loc);
            float m = siv + smax;
            m = (m >= 0.f) ? m : 0.2f * m;
            float z = 0.f;
            short* prow = &PSb[w][i_loc][0];
#pragma unroll
            for (int k = 0; k < 2; ++k) {
                int jj = k * 128 + lane * 2;
                int ja = idxS[w][jj], jb = idxS[w][jj + 1];
                float ava = adjbuf[r][ja], avb = adjbuf[r][jb];
                float ea = siv + sjS[w][jj];
                float eb = siv + sjS[w][jj + 1];
                ea = (ea >= 0.f) ? ea : 0.2f * ea;
                eb = (eb >= 0.f) ? eb : 0.2f * eb;
                float ca = __expf(ea - m);
                float cb = __expf(eb - m);
                z += ca + cb;
                short2 p;
                p.x = f2bf(ca * ava);
                p.y = f2bf(cb * avb);
                *(short2*)&prow[jj] = p;
            }
#pragma unroll
            for (int off = 32; off >= 1; off >>= 1) z += __shfl_xor(z, off);
            if (lane == 0) invZS[w][i_loc] = 1.0f / z;
        }
        if (s < 3) {
            __syncthreads();   // all waves done reading adjbuf
            float4* dst = (float4*)adjbuf;
#pragma unroll
            for (int q = 0; q < 8; ++q) dst[q * 256 + t] = pre[q];
            __syncthreads();
        }
    }
    // MFMA phase: PSb[w] is wave-private -> no barrier needed.
#pragma unroll
    for (int ni = 0; ni < 2; ++ni) {
        float4v acc = {0.f, 0.f, 0.f, 0.f};
#pragma unroll
        for (int ks = 0; ks < 8; ++ks) {
            short8 afr = *(const short8*)&PSb[w][mr][ks * 32 + quad * 8];
            acc = __builtin_amdgcn_mfma_f32_16x16x32_bf16(afr, bfr[ni][ks], acc, 0, 0, 0);
        }
#pragma unroll
        for (int r = 0; r < 4; ++r) {
            int i_loc = quad * 4 + r;
            int d = ni * 16 + mr;
            out[((size_t)(b * NN + i0 + i_loc)) * (HH * HD) + w * HD + d] =
                acc[r] * invZS[w][i_loc];
        }
    }
}

// ---------------------------------------------------------------------------
extern "C" void kernel_launch(void* const* d_in, const int* in_sizes, int n_in,
                              void* d_out, int out_size, void* d_ws, size_t ws_size,
                              hipStream_t stream) {
    const float* h   = (const float*)d_in[0];   // [B,N,DIN]
    const float* adj = (const float*)d_in[1];   // [B,N,N]
    const float* W   = (const float*)d_in[2];   // [H,DIN,HD]
    const float* a   = (const float*)d_in[3];   // [H,2*HD]
    float* out = (float*)d_out;                 // [B,N,H*HD]

    float* si     = (float*)d_ws;                        // BH*NN f32
    float* sj     = si + (size_t)BH * NN;                // BH*NN
    float* sjsel  = sj + (size_t)BH * NN;                // BH*KSEL
    float* sjmax  = sjsel + (size_t)BH * KSEL;           // BH (pad 16)
    int*   idxsel = (int*)(sjmax + 16);                  // BH*KSEL
    short* Whsel  = (short*)(idxsel + (size_t)BH * KSEL);// BH*HD*KPAD bf16

    s_kernel<<<BH * 8, 256, 0, stream>>>(h, W, a, si, sj);
    select_kernel<<<BH, 1024, 0, stream>>>(h, W, sj, idxsel, sjsel, sjmax, Whsel);
    attn2_kernel<<<BB * 128, 256, 0, stream>>>(adj, si, idxsel, sjsel, sjmax, Whsel, out);
}

// Round 3
// 130.090 us; speedup vs baseline: 1.1311x; 1.1311x over previous
//
#include <hip/hip_runtime.h>
#include <hip/hip_bf16.h>
#include <cmath>

#define BB 4
#define NN 2048
#define DIN 128
#define HH 4
#define HD 32
#define KSEL 204            // int(0.1 * 2048)
#define BH (BB*HH)
#define KPAD 256            // K padded to 8 MFMA steps of 32
#define KST 264             // PSb row stride (shorts): 132 words -> 2-way banks (free)

typedef __attribute__((ext_vector_type(8))) short short8;
typedef __attribute__((ext_vector_type(4))) short short4v;
typedef __attribute__((ext_vector_type(4))) float float4v;

static __device__ inline short f2bf(float x) {
    __hip_bfloat16 b = __float2bfloat16(x);   // RNE
    return __builtin_bit_cast(short, b);
}

// ---------------------------------------------------------------------------
// K1 v2: s_i = h.(W@a1), s_j = h.(W@a2) for ALL 4 heads per h-row read.
// h read ONCE (4 MB, was 16 MB). 128 blocks; 4 lanes per row, each lane owns
// a strided quarter of the features; w-vectors broadcast from LDS.
__global__ __launch_bounds__(256) void s_kernel(const float* __restrict__ h,
                                                const float* __restrict__ W,
                                                const float* __restrict__ a,
                                                float* __restrict__ si, float* __restrict__ sj) {
    __shared__ float w1L[HH][DIN], w2L[HH][DIN];
    int t = threadIdx.x;
    for (int e = t; e < 8 * DIN; e += 256) {
        int f = e & 127, v = e >> 7;          // v = head*2+half
        int hh = v >> 1, half = v & 1;
        const float* Wp = W + ((size_t)hh * DIN + f) * HD;
        const float* ap = a + hh * 64 + half * 32;
        float acc = 0.f;
#pragma unroll
        for (int d = 0; d < 32; ++d) acc += Wp[d] * ap[d];
        if (half == 0) w1L[hh][f] = acc; else w2L[hh][f] = acc;
    }
    __syncthreads();

    int gid = blockIdx.x * 256 + t;
    int row = gid >> 2;                       // 0..8191  (b*NN + n)
    int q   = gid & 3;                        // quarter-row lane
    int b = row >> 11, n = row & 2047;
    const float* hr = h + (size_t)row * DIN;

    float s1h0 = 0.f, s1h1 = 0.f, s1h2 = 0.f, s1h3 = 0.f;
    float s2h0 = 0.f, s2h1 = 0.f, s2h2 = 0.f, s2h3 = 0.f;
#pragma unroll
    for (int i = 0; i < 8; ++i) {
        int f = q * 4 + i * 16;
        float4 x = *(const float4*)(hr + f);
        const float* wa0 = &w1L[0][f]; const float* wb0 = &w2L[0][f];
        const float* wa1 = &w1L[1][f]; const float* wb1 = &w2L[1][f];
        const float* wa2 = &w1L[2][f]; const float* wb2 = &w2L[2][f];
        const float* wa3 = &w1L[3][f]; const float* wb3 = &w2L[3][f];
        s1h0 += x.x*wa0[0] + x.y*wa0[1] + x.z*wa0[2] + x.w*wa0[3];
        s2h0 += x.x*wb0[0] + x.y*wb0[1] + x.z*wb0[2] + x.w*wb0[3];
        s1h1 += x.x*wa1[0] + x.y*wa1[1] + x.z*wa1[2] + x.w*wa1[3];
        s2h1 += x.x*wb1[0] + x.y*wb1[1] + x.z*wb1[2] + x.w*wb1[3];
        s1h2 += x.x*wa2[0] + x.y*wa2[1] + x.z*wa2[2] + x.w*wa2[3];
        s2h2 += x.x*wb2[0] + x.y*wb2[1] + x.z*wb2[2] + x.w*wb2[3];
        s1h3 += x.x*wa3[0] + x.y*wa3[1] + x.z*wa3[2] + x.w*wa3[3];
        s2h3 += x.x*wb3[0] + x.y*wb3[1] + x.z*wb3[2] + x.w*wb3[3];
    }
#pragma unroll
    for (int off = 1; off <= 2; off <<= 1) {
        s1h0 += __shfl_xor(s1h0, off); s2h0 += __shfl_xor(s2h0, off);
        s1h1 += __shfl_xor(s1h1, off); s2h1 += __shfl_xor(s2h1, off);
        s1h2 += __shfl_xor(s1h2, off); s2h2 += __shfl_xor(s2h2, off);
        s1h3 += __shfl_xor(s1h3, off); s2h3 += __shfl_xor(s2h3, off);
    }
    float o1 = (q == 0) ? s1h0 : (q == 1) ? s1h1 : (q == 2) ? s1h2 : s1h3;
    float o2 = (q == 0) ? s2h0 : (q == 1) ? s2h1 : (q == 2) ? s2h2 : s2h3;
    size_t o = (size_t)(b * HH + q) * NN + n;
    si[o] = o1; sj[o] = o2;
}

// ---------------------------------------------------------------------------
// K2: select per (b,h), 1024 threads (16 waves):
//  radix-select top-KSEL (register keys, parallel suffix-scan), ordered
//  compaction, then Whsel[bh][d][jj] = bf16( h[sel jj] @ W[hh] ) via MFMA.
//  (only change vs round-0: WT load coalesced — consecutive threads read
//  consecutive d of W[hh][k][*] instead of stride-32.)
__global__ __launch_bounds__(1024) void select_kernel(
        const float* __restrict__ h, const float* __restrict__ W,
        const float* __restrict__ sj,
        int* __restrict__ idxsel, float* __restrict__ sjsel,
        float* __restrict__ sjmax, short* __restrict__ Whsel) {
    int bh = blockIdx.x;
    int b = bh >> 2, hh = bh & 3;
    int t = threadIdx.x, lane = t & 63, w = t >> 6;
    __shared__ float sv[NN];
    __shared__ short WT[32][136];            // WT[d][k] = bf16(W[hh][k][d])
    __shared__ int hist16[16][256];
    __shared__ int binInfo[2];               // [0]=Bsel, [1]=cum_before
    __shared__ int wtot[4];
    __shared__ int wtotg[16], wtote[16], woffg[16], woffe[16];
    __shared__ float wmax[16];
    __shared__ int idxLDS[KSEL];

    for (int e = t; e < 32 * 128; e += 1024) {
        int n = e & 31, k = e >> 5;          // coalesced: consecutive t -> consecutive d
        WT[n][k] = f2bf(W[(size_t)hh * (DIN * HD) + k * HD + n]);
    }

    // coalesced sj load; keys in registers
    const float* s = sj + (size_t)bh * NN;
    int j0 = t * 2;
    float2 xx = *(const float2*)(s + j0);
    sv[j0] = xx.x; sv[j0 + 1] = xx.y;
    unsigned u0 = __builtin_bit_cast(unsigned, xx.x);
    unsigned u1 = __builtin_bit_cast(unsigned, xx.y);
    u0 = (u0 & 0x80000000u) ? ~u0 : (u0 | 0x80000000u);
    u1 = (u1 & 0x80000000u) ? ~u1 : (u1 | 0x80000000u);
    float lmax = fmaxf(xx.x, xx.y);
#pragma unroll
    for (int off = 32; off >= 1; off >>= 1) lmax = fmaxf(lmax, __shfl_xor(lmax, off));
    if (lane == 0) wmax[w] = lmax;
    __syncthreads();
    if (t == 0) {
        float m = wmax[0];
#pragma unroll
        for (int i = 1; i < 16; ++i) m = fmaxf(m, wmax[i]);
        sjmax[bh] = m;
    }

    // radix: 4-pass byte histogram, parallel suffix-scan threshold search
    unsigned prefix = 0;
    int need = KSEL;
#pragma unroll
    for (int shift = 24; shift >= 0; shift -= 8) {
        ((int*)hist16)[t] = 0; ((int*)hist16)[t + 1024] = 0;
        ((int*)hist16)[t + 2048] = 0; ((int*)hist16)[t + 3072] = 0;
        __syncthreads();
        unsigned hmask = (shift < 24) ? (0xFFFFFFFFu << (shift + 8)) : 0u;
        if (((u0 ^ prefix) & hmask) == 0) atomicAdd(&hist16[w][(u0 >> shift) & 255], 1);
        if (((u1 ^ prefix) & hmask) == 0) atomicAdd(&hist16[w][(u1 >> shift) & 255], 1);
        __syncthreads();
        int sc = 0, hv = 0, bb = 0;
        if (t < 256) {                 // waves 0..3
            bb = 255 - t;
            hv = 0;
#pragma unroll
            for (int i = 0; i < 16; ++i) hv += hist16[i][bb];
            sc = hv;
#pragma unroll
            for (int off = 1; off < 64; off <<= 1) {
                int u = __shfl_up(sc, off);
                if (lane >= off) sc += u;
            }
            if (lane == 63) wtot[w] = sc;
        }
        __syncthreads();
        if (t < 256) {
            int woffset = 0;
#pragma unroll
            for (int i = 0; i < 4; ++i) woffset += (i < w) ? wtot[i] : 0;
            int incl = sc + woffset;
            int excl = incl - hv;
            if (incl >= need && excl < need) {   // unique thread
                binInfo[0] = bb;
                binInfo[1] = excl;
            }
        }
        __syncthreads();
        prefix |= ((unsigned)binInfo[0]) << shift;
        need -= binInfo[1];
        __syncthreads();
    }
    unsigned T = prefix;
    int n_gt = KSEL - need;        // count of keys strictly > T

    // ordered compaction (thread t owns j0, j0+1)
    int cg = (u0 > T ? 1 : 0) + (u1 > T ? 1 : 0);
    int ce = (u0 == T ? 1 : 0) + (u1 == T ? 1 : 0);
    int sg = cg, se = ce;
#pragma unroll
    for (int off = 1; off < 64; off <<= 1) {
        int ug = __shfl_up(sg, off), ue = __shfl_up(se, off);
        if (lane >= off) { sg += ug; se += ue; }
    }
    if (lane == 63) { wtotg[w] = sg; wtote[w] = se; }
    __syncthreads();
    if (t == 0) {
        int rg = 0, re = 0;
#pragma unroll
        for (int i = 0; i < 16; ++i) {
            woffg[i] = rg; rg += wtotg[i];
            woffe[i] = re; re += wtote[i];
        }
    }
    __syncthreads();
    int pg = woffg[w] + sg - cg;
    int te = woffe[w] + se - ce;
    {
        unsigned kk[2] = {u0, u1};
#pragma unroll
        for (int r = 0; r < 2; ++r) {
            int j = j0 + r;
            if (kk[r] > T) {
                idxsel[bh * KSEL + pg] = j;
                sjsel[bh * KSEL + pg] = sv[j];
                idxLDS[pg] = j;
                pg++;
            } else if (kk[r] == T) {
                if (te < need) {
                    int pos = n_gt + te;
                    idxsel[bh * KSEL + pos] = j;
                    sjsel[bh * KSEL + pos] = sv[j];
                    idxLDS[pos] = j;
                }
                te++;
            }
        }
    }
    __syncthreads();

    // Phase D: Whsel[bh][d][jj] = bf16( h[idxLDS[jj]] @ W[hh] ), tail zero.
    {
        int mr = lane & 15, quad = lane >> 4;
        int jjp = w * 16 + mr;
        bool valid = jjp < KSEL;
        const float* hrow = h + ((size_t)b * NN + (valid ? idxLDS[jjp] : 0)) * DIN + quad * 8;
        float4v acc0 = {0.f, 0.f, 0.f, 0.f};
        float4v acc1 = {0.f, 0.f, 0.f, 0.f};
#pragma unroll
        for (int ks = 0; ks < 4; ++ks) {
            short8 afr;
            if (valid) {
                float4 xa = *(const float4*)(hrow + ks * 32);
                float4 xb = *(const float4*)(hrow + ks * 32 + 4);
                afr[0] = f2bf(xa.x); afr[1] = f2bf(xa.y); afr[2] = f2bf(xa.z); afr[3] = f2bf(xa.w);
                afr[4] = f2bf(xb.x); afr[5] = f2bf(xb.y); afr[6] = f2bf(xb.z); afr[7] = f2bf(xb.w);
            } else {
                afr = (short8){0, 0, 0, 0, 0, 0, 0, 0};
            }
            short8 b0 = *(const short8*)&WT[mr][ks * 32 + quad * 8];
            short8 b1 = *(const short8*)&WT[16 + mr][ks * 32 + quad * 8];
            acc0 = __builtin_amdgcn_mfma_f32_16x16x32_bf16(afr, b0, acc0, 0, 0, 0);
            acc1 = __builtin_amdgcn_mfma_f32_16x16x32_bf16(afr, b1, acc1, 0, 0, 0);
        }
        short4v o0, o1;
#pragma unroll
        for (int r = 0; r < 4; ++r) { o0[r] = f2bf(acc0[r]); o1[r] = f2bf(acc1[r]); }
        size_t base = (size_t)bh * HD * KPAD;
        int jjs = w * 16 + quad * 4;
        *(short4v*)&Whsel[base + (size_t)mr * KPAD + jjs] = o0;
        *(short4v*)&Whsel[base + (size_t)(16 + mr) * KPAD + jjs] = o1;
    }
}

// ---------------------------------------------------------------------------
// K3: FUSED attention. Block = (b, 16 rows, 4 heads-as-waves), grid 512.
// EXACT round-0 structure (measured ~24 us): 4 dense adj rows -> LDS per
// stage, loads issued between the two barriers; wave w computes head w's P
// rows into its PRIVATE PSb[w]; then MFMA. ~75 KB LDS, 2 blocks/CU.
__global__ __launch_bounds__(256) void attn2_kernel(
        const float* __restrict__ adj, const float* __restrict__ si,
        const int* __restrict__ idxsel, const float* __restrict__ sjsel,
        const float* __restrict__ sjmax, const short* __restrict__ Whsel,
        float* __restrict__ out) {
    int b = blockIdx.x >> 7;        // 4
    int tile = blockIdx.x & 127;    // 128 tiles of 16 rows
    __shared__ float adjbuf[4][NN];          // 32 KB
    __shared__ short PSb[HH][16][KST];       // 33 KB, per-head private
    __shared__ int   idxS[HH][KPAD];         // 4 KB
    __shared__ float sjS[HH][KPAD];          // 4 KB
    __shared__ float invZS[HH][16];
    __shared__ float smaxS[HH];
    int t = threadIdx.x, w = t >> 6, lane = t & 63;
    int mr = lane & 15, quad = lane >> 4;

    // padded per-head tables
    for (int e = t; e < HH * KPAD; e += 256) {
        int hh = e >> 8, jj = e & 255;
        bool v = jj < KSEL;
        idxS[hh][jj] = v ? idxsel[(b * HH + hh) * KSEL + jj] : 0;
        sjS[hh][jj]  = v ? sjsel[(b * HH + hh) * KSEL + jj] : -1e30f;
    }
    if (t < HH) smaxS[t] = sjmax[b * HH + t];

    // B-fragments for head w (registers, reused all block)
    short8 bfr[2][8];
    {
        const short* wp = Whsel + (size_t)((b * HH + w) * HD) * KPAD;
#pragma unroll
        for (int ni = 0; ni < 2; ++ni)
#pragma unroll
            for (int ks = 0; ks < 8; ++ks)
                bfr[ni][ks] = *(const short8*)(wp + (size_t)(ni * 16 + mr) * KPAD + ks * 32 + quad * 8);
    }

    int i0 = tile * 16;
    const float* adjb = adj + (size_t)b * NN * NN;
    // stage 0: 4 dense adj rows
    {
        const float4* src = (const float4*)(adjb + (size_t)i0 * NN);
        float4* dst = (float4*)adjbuf;
#pragma unroll
        for (int q = 0; q < 8; ++q)
            dst[q * 256 + t] = src[q * 256 + t];
    }
    __syncthreads();

    int bh = b * HH + w;
    float smax = smaxS[w];
    for (int s = 0; s < 4; ++s) {
#pragma unroll
        for (int r = 0; r < 4; ++r) {
            int i_loc = s * 4 + r;
            int i = i0 + i_loc;
            float siv = si[(size_t)bh * NN + i];
            float m = siv + smax;
            m = (m >= 0.f) ? m : 0.2f * m;
            float z = 0.f;
            short* prow = &PSb[w][i_loc][0];
#pragma unroll
            for (int k = 0; k < 2; ++k) {
                int jj = k * 128 + lane * 2;
                int ja = idxS[w][jj], jb = idxS[w][jj + 1];
                float ava = adjbuf[r][ja], avb = adjbuf[r][jb];
                float ea = siv + sjS[w][jj];
                float eb = siv + sjS[w][jj + 1];
                ea = (ea >= 0.f) ? ea : 0.2f * ea;
                eb = (eb >= 0.f) ? eb : 0.2f * eb;
                float ca = __expf(ea - m);
                float cb = __expf(eb - m);
                z += ca + cb;
                short2 p;
                p.x = f2bf(ca * ava);
                p.y = f2bf(cb * avb);
                *(short2*)&prow[jj] = p;
            }
#pragma unroll
            for (int off = 32; off >= 1; off >>= 1) z += __shfl_xor(z, off);
            if (lane == 0) invZS[w][i_loc] = 1.0f / z;
        }
        if (s < 3) {
            __syncthreads();   // all waves done reading adjbuf
            const float4* src = (const float4*)(adjb + (size_t)(i0 + (s + 1) * 4) * NN);
            float4* dst = (float4*)adjbuf;
#pragma unroll
            for (int q = 0; q < 8; ++q)
                dst[q * 256 + t] = src[q * 256 + t];
            __syncthreads();
        }
    }
    // MFMA phase: PSb[w] is wave-private -> no barrier needed.
#pragma unroll
    for (int ni = 0; ni < 2; ++ni) {
        float4v acc = {0.f, 0.f, 0.f, 0.f};
#pragma unroll
        for (int ks = 0; ks < 8; ++ks) {
            short8 afr = *(const short8*)&PSb[w][mr][ks * 32 + quad * 8];
            acc = __builtin_amdgcn_mfma_f32_16x16x32_bf16(afr, bfr[ni][ks], acc, 0, 0, 0);
        }
#pragma unroll
        for (int r = 0; r < 4; ++r) {
            int i_loc = quad * 4 + r;
            int d = ni * 16 + mr;
            out[((size_t)(b * NN + i0 + i_loc)) * (HH * HD) + w * HD + d] =
                acc[r] * invZS[w][i_loc];
        }
    }
}

// ---------------------------------------------------------------------------
extern "C" void kernel_launch(void* const* d_in, const int* in_sizes, int n_in,
                              void* d_out, int out_size, void* d_ws, size_t ws_size,
                              hipStream_t stream) {
    const float* h   = (const float*)d_in[0];   // [B,N,DIN]
    const float* adj = (const float*)d_in[1];   // [B,N,N]
    const float* W   = (const float*)d_in[2];   // [H,DIN,HD]
    const float* a   = (const float*)d_in[3];   // [H,2*HD]
    float* out = (float*)d_out;                 // [B,N,H*HD]

    float* si     = (float*)d_ws;                        // BH*NN f32
    float* sj     = si + (size_t)BH * NN;                // BH*NN
    float* sjsel  = sj + (size_t)BH * NN;                // BH*KSEL
    float* sjmax  = sjsel + (size_t)BH * KSEL;           // BH (pad 16)
    int*   idxsel = (int*)(sjmax + 16);                  // BH*KSEL
    short* Whsel  = (short*)(idxsel + (size_t)BH * KSEL);// BH*HD*KPAD bf16

    s_kernel<<<128, 256, 0, stream>>>(h, W, a, si, sj);
    select_kernel<<<BH, 1024, 0, stream>>>(h, W, sj, idxsel, sjsel, sjmax, Whsel);
    attn2_kernel<<<BB * 128, 256, 0, stream>>>(adj, si, idxsel, sjsel, sjmax, Whsel, out);
}

// Round 4
// 128.883 us; speedup vs baseline: 1.1417x; 1.0094x over previous
//
#include <hip/hip_runtime.h>
#include <hip/hip_bf16.h>
#include <cmath>

#define BB 4
#define NN 2048
#define DIN 128
#define HH 4
#define HD 32
#define KSEL 204            // int(0.1 * 2048)
#define BH (BB*HH)
#define KPAD 256            // K padded to 8 MFMA steps of 32
#define KST 264             // PSb row stride (shorts): 132 words -> 2-way banks (free)

typedef __attribute__((ext_vector_type(8))) short short8;
typedef __attribute__((ext_vector_type(4))) short short4v;
typedef __attribute__((ext_vector_type(4))) float float4v;

static __device__ inline short f2bf(float x) {
    __hip_bfloat16 b = __float2bfloat16(x);   // RNE
    return __builtin_bit_cast(short, b);
}

// global -> LDS direct copy, 16B per lane (wave-uniform LDS base + lane*16)
typedef __attribute__((address_space(1))) const unsigned gq_t;
typedef __attribute__((address_space(3))) unsigned lq_t;
static __device__ inline void gload_lds16(const void* g, void* l) {
    __builtin_amdgcn_global_load_lds((gq_t*)g, (lq_t*)l, 16, 0, 0);
}

// ---------------------------------------------------------------------------
// K1 v2: s_i = h.(W@a1), s_j = h.(W@a2) for ALL 4 heads per h-row read.
__global__ __launch_bounds__(256) void s_kernel(const float* __restrict__ h,
                                                const float* __restrict__ W,
                                                const float* __restrict__ a,
                                                float* __restrict__ si, float* __restrict__ sj) {
    __shared__ float w1L[HH][DIN], w2L[HH][DIN];
    int t = threadIdx.x;
    for (int e = t; e < 8 * DIN; e += 256) {
        int f = e & 127, v = e >> 7;          // v = head*2+half
        int hh = v >> 1, half = v & 1;
        const float* Wp = W + ((size_t)hh * DIN + f) * HD;
        const float* ap = a + hh * 64 + half * 32;
        float acc = 0.f;
#pragma unroll
        for (int d = 0; d < 32; ++d) acc += Wp[d] * ap[d];
        if (half == 0) w1L[hh][f] = acc; else w2L[hh][f] = acc;
    }
    __syncthreads();

    int gid = blockIdx.x * 256 + t;
    int row = gid >> 2;                       // 0..8191  (b*NN + n)
    int q   = gid & 3;                        // quarter-row lane
    int b = row >> 11, n = row & 2047;
    const float* hr = h + (size_t)row * DIN;

    float s1h0 = 0.f, s1h1 = 0.f, s1h2 = 0.f, s1h3 = 0.f;
    float s2h0 = 0.f, s2h1 = 0.f, s2h2 = 0.f, s2h3 = 0.f;
#pragma unroll
    for (int i = 0; i < 8; ++i) {
        int f = q * 4 + i * 16;
        float4 x = *(const float4*)(hr + f);
        const float* wa0 = &w1L[0][f]; const float* wb0 = &w2L[0][f];
        const float* wa1 = &w1L[1][f]; const float* wb1 = &w2L[1][f];
        const float* wa2 = &w1L[2][f]; const float* wb2 = &w2L[2][f];
        const float* wa3 = &w1L[3][f]; const float* wb3 = &w2L[3][f];
        s1h0 += x.x*wa0[0] + x.y*wa0[1] + x.z*wa0[2] + x.w*wa0[3];
        s2h0 += x.x*wb0[0] + x.y*wb0[1] + x.z*wb0[2] + x.w*wb0[3];
        s1h1 += x.x*wa1[0] + x.y*wa1[1] + x.z*wa1[2] + x.w*wa1[3];
        s2h1 += x.x*wb1[0] + x.y*wb1[1] + x.z*wb1[2] + x.w*wb1[3];
        s1h2 += x.x*wa2[0] + x.y*wa2[1] + x.z*wa2[2] + x.w*wa2[3];
        s2h2 += x.x*wb2[0] + x.y*wb2[1] + x.z*wb2[2] + x.w*wb2[3];
        s1h3 += x.x*wa3[0] + x.y*wa3[1] + x.z*wa3[2] + x.w*wa3[3];
        s2h3 += x.x*wb3[0] + x.y*wb3[1] + x.z*wb3[2] + x.w*wb3[3];
    }
#pragma unroll
    for (int off = 1; off <= 2; off <<= 1) {
        s1h0 += __shfl_xor(s1h0, off); s2h0 += __shfl_xor(s2h0, off);
        s1h1 += __shfl_xor(s1h1, off); s2h1 += __shfl_xor(s2h1, off);
        s1h2 += __shfl_xor(s1h2, off); s2h2 += __shfl_xor(s2h2, off);
        s1h3 += __shfl_xor(s1h3, off); s2h3 += __shfl_xor(s2h3, off);
    }
    float o1 = (q == 0) ? s1h0 : (q == 1) ? s1h1 : (q == 2) ? s1h2 : s1h3;
    float o2 = (q == 0) ? s2h0 : (q == 1) ? s2h1 : (q == 2) ? s2h2 : s2h3;
    size_t o = (size_t)(b * HH + q) * NN + n;
    si[o] = o1; sj[o] = o2;
}

// ---------------------------------------------------------------------------
// K2: select per (b,h), 1024 threads (16 waves). Unchanged from round 3.
__global__ __launch_bounds__(1024) void select_kernel(
        const float* __restrict__ h, const float* __restrict__ W,
        const float* __restrict__ sj,
        int* __restrict__ idxsel, float* __restrict__ sjsel,
        float* __restrict__ sjmax, short* __restrict__ Whsel) {
    int bh = blockIdx.x;
    int b = bh >> 2, hh = bh & 3;
    int t = threadIdx.x, lane = t & 63, w = t >> 6;
    __shared__ float sv[NN];
    __shared__ short WT[32][136];            // WT[d][k] = bf16(W[hh][k][d])
    __shared__ int hist16[16][256];
    __shared__ int binInfo[2];               // [0]=Bsel, [1]=cum_before
    __shared__ int wtot[4];
    __shared__ int wtotg[16], wtote[16], woffg[16], woffe[16];
    __shared__ float wmax[16];
    __shared__ int idxLDS[KSEL];

    for (int e = t; e < 32 * 128; e += 1024) {
        int n = e & 31, k = e >> 5;          // coalesced: consecutive t -> consecutive d
        WT[n][k] = f2bf(W[(size_t)hh * (DIN * HD) + k * HD + n]);
    }

    // coalesced sj load; keys in registers
    const float* s = sj + (size_t)bh * NN;
    int j0 = t * 2;
    float2 xx = *(const float2*)(s + j0);
    sv[j0] = xx.x; sv[j0 + 1] = xx.y;
    unsigned u0 = __builtin_bit_cast(unsigned, xx.x);
    unsigned u1 = __builtin_bit_cast(unsigned, xx.y);
    u0 = (u0 & 0x80000000u) ? ~u0 : (u0 | 0x80000000u);
    u1 = (u1 & 0x80000000u) ? ~u1 : (u1 | 0x80000000u);
    float lmax = fmaxf(xx.x, xx.y);
#pragma unroll
    for (int off = 32; off >= 1; off >>= 1) lmax = fmaxf(lmax, __shfl_xor(lmax, off));
    if (lane == 0) wmax[w] = lmax;
    __syncthreads();
    if (t == 0) {
        float m = wmax[0];
#pragma unroll
        for (int i = 1; i < 16; ++i) m = fmaxf(m, wmax[i]);
        sjmax[bh] = m;
    }

    // radix: 4-pass byte histogram, parallel suffix-scan threshold search
    unsigned prefix = 0;
    int need = KSEL;
#pragma unroll
    for (int shift = 24; shift >= 0; shift -= 8) {
        ((int*)hist16)[t] = 0; ((int*)hist16)[t + 1024] = 0;
        ((int*)hist16)[t + 2048] = 0; ((int*)hist16)[t + 3072] = 0;
        __syncthreads();
        unsigned hmask = (shift < 24) ? (0xFFFFFFFFu << (shift + 8)) : 0u;
        if (((u0 ^ prefix) & hmask) == 0) atomicAdd(&hist16[w][(u0 >> shift) & 255], 1);
        if (((u1 ^ prefix) & hmask) == 0) atomicAdd(&hist16[w][(u1 >> shift) & 255], 1);
        __syncthreads();
        int sc = 0, hv = 0, bb = 0;
        if (t < 256) {                 // waves 0..3
            bb = 255 - t;
            hv = 0;
#pragma unroll
            for (int i = 0; i < 16; ++i) hv += hist16[i][bb];
            sc = hv;
#pragma unroll
            for (int off = 1; off < 64; off <<= 1) {
                int u = __shfl_up(sc, off);
                if (lane >= off) sc += u;
            }
            if (lane == 63) wtot[w] = sc;
        }
        __syncthreads();
        if (t < 256) {
            int woffset = 0;
#pragma unroll
            for (int i = 0; i < 4; ++i) woffset += (i < w) ? wtot[i] : 0;
            int incl = sc + woffset;
            int excl = incl - hv;
            if (incl >= need && excl < need) {   // unique thread
                binInfo[0] = bb;
                binInfo[1] = excl;
            }
        }
        __syncthreads();
        prefix |= ((unsigned)binInfo[0]) << shift;
        need -= binInfo[1];
        __syncthreads();
    }
    unsigned T = prefix;
    int n_gt = KSEL - need;        // count of keys strictly > T

    // ordered compaction (thread t owns j0, j0+1)
    int cg = (u0 > T ? 1 : 0) + (u1 > T ? 1 : 0);
    int ce = (u0 == T ? 1 : 0) + (u1 == T ? 1 : 0);
    int sg = cg, se = ce;
#pragma unroll
    for (int off = 1; off < 64; off <<= 1) {
        int ug = __shfl_up(sg, off), ue = __shfl_up(se, off);
        if (lane >= off) { sg += ug; se += ue; }
    }
    if (lane == 63) { wtotg[w] = sg; wtote[w] = se; }
    __syncthreads();
    if (t == 0) {
        int rg = 0, re = 0;
#pragma unroll
        for (int i = 0; i < 16; ++i) {
            woffg[i] = rg; rg += wtotg[i];
            woffe[i] = re; re += wtote[i];
        }
    }
    __syncthreads();
    int pg = woffg[w] + sg - cg;
    int te = woffe[w] + se - ce;
    {
        unsigned kk[2] = {u0, u1};
#pragma unroll
        for (int r = 0; r < 2; ++r) {
            int j = j0 + r;
            if (kk[r] > T) {
                idxsel[bh * KSEL + pg] = j;
                sjsel[bh * KSEL + pg] = sv[j];
                idxLDS[pg] = j;
                pg++;
            } else if (kk[r] == T) {
                if (te < need) {
                    int pos = n_gt + te;
                    idxsel[bh * KSEL + pos] = j;
                    sjsel[bh * KSEL + pos] = sv[j];
                    idxLDS[pos] = j;
                }
                te++;
            }
        }
    }
    __syncthreads();

    // Phase D: Whsel[bh][d][jj] = bf16( h[idxLDS[jj]] @ W[hh] ), tail zero.
    {
        int mr = lane & 15, quad = lane >> 4;
        int jjp = w * 16 + mr;
        bool valid = jjp < KSEL;
        const float* hrow = h + ((size_t)b * NN + (valid ? idxLDS[jjp] : 0)) * DIN + quad * 8;
        float4v acc0 = {0.f, 0.f, 0.f, 0.f};
        float4v acc1 = {0.f, 0.f, 0.f, 0.f};
#pragma unroll
        for (int ks = 0; ks < 4; ++ks) {
            short8 afr;
            if (valid) {
                float4 xa = *(const float4*)(hrow + ks * 32);
                float4 xb = *(const float4*)(hrow + ks * 32 + 4);
                afr[0] = f2bf(xa.x); afr[1] = f2bf(xa.y); afr[2] = f2bf(xa.z); afr[3] = f2bf(xa.w);
                afr[4] = f2bf(xb.x); afr[5] = f2bf(xb.y); afr[6] = f2bf(xb.z); afr[7] = f2bf(xb.w);
            } else {
                afr = (short8){0, 0, 0, 0, 0, 0, 0, 0};
            }
            short8 b0 = *(const short8*)&WT[mr][ks * 32 + quad * 8];
            short8 b1 = *(const short8*)&WT[16 + mr][ks * 32 + quad * 8];
            acc0 = __builtin_amdgcn_mfma_f32_16x16x32_bf16(afr, b0, acc0, 0, 0, 0);
            acc1 = __builtin_amdgcn_mfma_f32_16x16x32_bf16(afr, b1, acc1, 0, 0, 0);
        }
        short4v o0, o1;
#pragma unroll
        for (int r = 0; r < 4; ++r) { o0[r] = f2bf(acc0[r]); o1[r] = f2bf(acc1[r]); }
        size_t base = (size_t)bh * HD * KPAD;
        int jjs = w * 16 + quad * 4;
        *(short4v*)&Whsel[base + (size_t)mr * KPAD + jjs] = o0;
        *(short4v*)&Whsel[base + (size_t)(16 + mr) * KPAD + jjs] = o1;
    }
}

// ---------------------------------------------------------------------------
// K3 v3: FUSED attention with T3/T4 pipeline. Block = (b, 16 rows, 4
// heads-as-waves), grid 512. adj staged via global_load_lds (16B/lane, no
// VGPR round-trip) into a 2x16KB double buffer (2 rows/stage, 8 stages).
// Raw s_barrier + counted vmcnt: loads for stage s+1 fly DURING stage-s
// compute; no full drain before compute. Steady loop has ZERO other VMEM
// (si pre-broadcast via shfl). Compute math / PSb / MFMA identical to r0.
__global__ __launch_bounds__(256) void attn2_kernel(
        const float* __restrict__ adj, const float* __restrict__ si,
        const int* __restrict__ idxsel, const float* __restrict__ sjsel,
        const float* __restrict__ sjmax, const short* __restrict__ Whsel,
        float* __restrict__ out) {
    int b = blockIdx.x >> 7;        // 4
    int tile = blockIdx.x & 127;    // 128 tiles of 16 rows
    __shared__ float adjbuf[2][2][NN];       // 32 KB double buffer, 2 rows/stage
    __shared__ short PSb[HH][16][KST];       // 33 KB, per-head private
    __shared__ int   idxS[HH][KPAD];         // 4 KB
    __shared__ float sjS[HH][KPAD];          // 4 KB
    __shared__ float invZS[HH][16];
    __shared__ float smaxS[HH];
    int t = threadIdx.x, w = t >> 6, lane = t & 63;
    int mr = lane & 15, quad = lane >> 4;

    int i0 = tile * 16;
    const float* adjb = adj + (size_t)b * NN * NN + (size_t)i0 * NN;

    // ---- prologue: tables + B-fragments + si (all VMEM completes at the
    // __syncthreads below -> clean vmcnt slate for the pipeline) ----
    for (int e = t; e < HH * KPAD; e += 256) {
        int hh = e >> 8, jj = e & 255;
        bool v = jj < KSEL;
        idxS[hh][jj] = v ? idxsel[(b * HH + hh) * KSEL + jj] : 0;
        sjS[hh][jj]  = v ? sjsel[(b * HH + hh) * KSEL + jj] : -1e30f;
    }
    if (t < HH) smaxS[t] = sjmax[b * HH + t];

    short8 bfr[2][8];
    {
        const short* wp = Whsel + (size_t)((b * HH + w) * HD) * KPAD;
#pragma unroll
        for (int ni = 0; ni < 2; ++ni)
#pragma unroll
            for (int ks = 0; ks < 8; ++ks)
                bfr[ni][ks] = *(const short8*)(wp + (size_t)(ni * 16 + mr) * KPAD + ks * 32 + quad * 8);
    }
    int bh = b * HH + w;
    float sivAll = (lane < 16) ? si[(size_t)bh * NN + i0 + lane] : 0.f;

    __syncthreads();   // publishes idxS/sjS/smaxS; drains vmcnt to 0

    // ---- pipeline prologue: issue stage 0 -> buf0, stage 1 -> buf1 ----
    // thread t copies 64B of the 16KB stage: chunk q at (q*4096 + w*1024 +
    // lane*16). LDS dest base is wave-uniform (lane*16 added by HW).
    {
        int lx = lane << 4;
#pragma unroll
        for (int q = 0; q < 4; ++q) {
            int off = (q << 12) + (w << 10);
            gload_lds16((const char*)adjb + off + lx, (char*)&adjbuf[0][0][0] + off);
        }
        const char* gs1 = (const char*)(adjb + (size_t)2 * NN);
#pragma unroll
        for (int q = 0; q < 4; ++q) {
            int off = (q << 12) + (w << 10);
            gload_lds16(gs1 + off + lx, (char*)&adjbuf[1][0][0] + off);
        }
    }
    asm volatile("s_waitcnt vmcnt(4)" ::: "memory");   // stage-0's 4 done; stage-1 in flight
    __builtin_amdgcn_sched_barrier(0);
    __builtin_amdgcn_s_barrier();

    float smax = smaxS[w];
    for (int s = 0; s < 8; ++s) {
        int cur = s & 1;
        // issue stage s+1 loads (buffer cur^1 was released by the previous
        // barrier; for s==0 stage 1 was issued in the prologue)
        if (s >= 1 && s < 7) {
            const char* gs = (const char*)(adjb + (size_t)((s + 1) * 2) * NN);
            char* lb = (char*)&adjbuf[cur ^ 1][0][0];
            int lx = lane << 4;
#pragma unroll
            for (int q = 0; q < 4; ++q) {
                int off = (q << 12) + (w << 10);
                gload_lds16(gs + off + lx, lb + off);
            }
        }
        // compute 2 rows from adjbuf[cur] (no VMEM in here)
#pragma unroll
        for (int r = 0; r < 2; ++r) {
            int i_loc = s * 2 + r;
            float siv = __shfl(sivAll, i_loc);
            float m = siv + smax;
            m = (m >= 0.f) ? m : 0.2f * m;
            float z = 0.f;
            short* prow = &PSb[w][i_loc][0];
#pragma unroll
            for (int k = 0; k < 2; ++k) {
                int jj = k * 128 + lane * 2;
                int ja = idxS[w][jj], jb = idxS[w][jj + 1];
                float ava = adjbuf[cur][r][ja], avb = adjbuf[cur][r][jb];
                float ea = siv + sjS[w][jj];
                float eb = siv + sjS[w][jj + 1];
                ea = (ea >= 0.f) ? ea : 0.2f * ea;
                eb = (eb >= 0.f) ? eb : 0.2f * eb;
                float ca = __expf(ea - m);
                float cb = __expf(eb - m);
                z += ca + cb;
                short2 p;
                p.x = f2bf(ca * ava);
                p.y = f2bf(cb * avb);
                *(short2*)&prow[jj] = p;
            }
#pragma unroll
            for (int off = 32; off >= 1; off >>= 1) z += __shfl_xor(z, off);
            if (lane == 0) invZS[w][i_loc] = 1.0f / z;
        }
        if (s < 7) {
            // wait for OUR stage-(s+1) loads (the only outstanding VMEM),
            // then sync waves: buffer cur^1 is now fully populated for all.
            asm volatile("s_waitcnt vmcnt(0)" ::: "memory");
            __builtin_amdgcn_sched_barrier(0);
            __builtin_amdgcn_s_barrier();
        }
    }
    // MFMA phase: PSb[w] is wave-private -> no barrier needed.
#pragma unroll
    for (int ni = 0; ni < 2; ++ni) {
        float4v acc = {0.f, 0.f, 0.f, 0.f};
#pragma unroll
        for (int ks = 0; ks < 8; ++ks) {
            short8 afr = *(const short8*)&PSb[w][mr][ks * 32 + quad * 8];
            acc = __builtin_amdgcn_mfma_f32_16x16x32_bf16(afr, bfr[ni][ks], acc, 0, 0, 0);
        }
#pragma unroll
        for (int r = 0; r < 4; ++r) {
            int i_loc = quad * 4 + r;
            int d = ni * 16 + mr;
            out[((size_t)(b * NN + i0 + i_loc)) * (HH * HD) + w * HD + d] =
                acc[r] * invZS[w][i_loc];
        }
    }
}

// ---------------------------------------------------------------------------
extern "C" void kernel_launch(void* const* d_in, const int* in_sizes, int n_in,
                              void* d_out, int out_size, void* d_ws, size_t ws_size,
                              hipStream_t stream) {
    const float* h   = (const float*)d_in[0];   // [B,N,DIN]
    const float* adj = (const float*)d_in[1];   // [B,N,N]
    const float* W   = (const float*)d_in[2];   // [H,DIN,HD]
    const float* a   = (const float*)d_in[3];   // [H,2*HD]
    float* out = (float*)d_out;                 // [B,N,H*HD]

    float* si     = (float*)d_ws;                        // BH*NN f32
    float* sj     = si + (size_t)BH * NN;                // BH*NN
    float* sjsel  = sj + (size_t)BH * NN;                // BH*KSEL
    float* sjmax  = sjsel + (size_t)BH * KSEL;           // BH (pad 16)
    int*   idxsel = (int*)(sjmax + 16);                  // BH*KSEL
    short* Whsel  = (short*)(idxsel + (size_t)BH * KSEL);// BH*HD*KPAD bf16

    s_kernel<<<128, 256, 0, stream>>>(h, W, a, si, sj);
    select_kernel<<<BH, 1024, 0, stream>>>(h, W, sj, idxsel, sjsel, sjmax, Whsel);
    attn2_kernel<<<BB * 128, 256, 0, stream>>>(adj, si, idxsel, sjsel, sjmax, Whsel, out);
}

// Round 5
// 126.474 us; speedup vs baseline: 1.1635x; 1.0190x over previous
//
#include <hip/hip_runtime.h>
#include <hip/hip_bf16.h>
#include <cmath>

#define BB 4
#define NN 2048
#define DIN 128
#define HH 4
#define HD 32
#define KSEL 204            // int(0.1 * 2048)
#define BH (BB*HH)
#define KPAD 256            // K padded to 8 MFMA steps of 32
#define KST 264             // PSb row stride (shorts): 132 words -> 2-way banks (free)

typedef __attribute__((ext_vector_type(8))) short short8;
typedef __attribute__((ext_vector_type(4))) short short4v;
typedef __attribute__((ext_vector_type(4))) float float4v;

static __device__ inline short f2bf(float x) {
    __hip_bfloat16 b = __float2bfloat16(x);   // RNE
    return __builtin_bit_cast(short, b);
}

// global -> LDS direct copy, 16B per lane (wave-uniform LDS base + lane*16)
typedef __attribute__((address_space(1))) const unsigned gq_t;
typedef __attribute__((address_space(3))) unsigned lq_t;
static __device__ inline void gload_lds16(const void* g, void* l) {
    __builtin_amdgcn_global_load_lds((gq_t*)g, (lq_t*)l, 16, 0, 0);
}

// ---------------------------------------------------------------------------
// K1 v2: s_i = h.(W@a1), s_j = h.(W@a2) for ALL 4 heads per h-row read.
__global__ __launch_bounds__(256) void s_kernel(const float* __restrict__ h,
                                                const float* __restrict__ W,
                                                const float* __restrict__ a,
                                                float* __restrict__ si, float* __restrict__ sj) {
    __shared__ float w1L[HH][DIN], w2L[HH][DIN];
    int t = threadIdx.x;
    for (int e = t; e < 8 * DIN; e += 256) {
        int f = e & 127, v = e >> 7;          // v = head*2+half
        int hh = v >> 1, half = v & 1;
        const float* Wp = W + ((size_t)hh * DIN + f) * HD;
        const float* ap = a + hh * 64 + half * 32;
        float acc = 0.f;
#pragma unroll
        for (int d = 0; d < 32; ++d) acc += Wp[d] * ap[d];
        if (half == 0) w1L[hh][f] = acc; else w2L[hh][f] = acc;
    }
    __syncthreads();

    int gid = blockIdx.x * 256 + t;
    int row = gid >> 2;                       // 0..8191  (b*NN + n)
    int q   = gid & 3;                        // quarter-row lane
    int b = row >> 11, n = row & 2047;
    const float* hr = h + (size_t)row * DIN;

    float s1h0 = 0.f, s1h1 = 0.f, s1h2 = 0.f, s1h3 = 0.f;
    float s2h0 = 0.f, s2h1 = 0.f, s2h2 = 0.f, s2h3 = 0.f;
#pragma unroll
    for (int i = 0; i < 8; ++i) {
        int f = q * 4 + i * 16;
        float4 x = *(const float4*)(hr + f);
        const float* wa0 = &w1L[0][f]; const float* wb0 = &w2L[0][f];
        const float* wa1 = &w1L[1][f]; const float* wb1 = &w2L[1][f];
        const float* wa2 = &w1L[2][f]; const float* wb2 = &w2L[2][f];
        const float* wa3 = &w1L[3][f]; const float* wb3 = &w2L[3][f];
        s1h0 += x.x*wa0[0] + x.y*wa0[1] + x.z*wa0[2] + x.w*wa0[3];
        s2h0 += x.x*wb0[0] + x.y*wb0[1] + x.z*wb0[2] + x.w*wb0[3];
        s1h1 += x.x*wa1[0] + x.y*wa1[1] + x.z*wa1[2] + x.w*wa1[3];
        s2h1 += x.x*wb1[0] + x.y*wb1[1] + x.z*wb1[2] + x.w*wb1[3];
        s1h2 += x.x*wa2[0] + x.y*wa2[1] + x.z*wa2[2] + x.w*wa2[3];
        s2h2 += x.x*wb2[0] + x.y*wb2[1] + x.z*wb2[2] + x.w*wb2[3];
        s1h3 += x.x*wa3[0] + x.y*wa3[1] + x.z*wa3[2] + x.w*wa3[3];
        s2h3 += x.x*wb3[0] + x.y*wb3[1] + x.z*wb3[2] + x.w*wb3[3];
    }
#pragma unroll
    for (int off = 1; off <= 2; off <<= 1) {
        s1h0 += __shfl_xor(s1h0, off); s2h0 += __shfl_xor(s2h0, off);
        s1h1 += __shfl_xor(s1h1, off); s2h1 += __shfl_xor(s2h1, off);
        s1h2 += __shfl_xor(s1h2, off); s2h2 += __shfl_xor(s2h2, off);
        s1h3 += __shfl_xor(s1h3, off); s2h3 += __shfl_xor(s2h3, off);
    }
    float o1 = (q == 0) ? s1h0 : (q == 1) ? s1h1 : (q == 2) ? s1h2 : s1h3;
    float o2 = (q == 0) ? s2h0 : (q == 1) ? s2h1 : (q == 2) ? s2h2 : s2h3;
    size_t o = (size_t)(b * HH + q) * NN + n;
    si[o] = o1; sj[o] = o2;
}

// ---------------------------------------------------------------------------
// K2: select per (b,h), 1024 threads (16 waves). Unchanged.
__global__ __launch_bounds__(1024) void select_kernel(
        const float* __restrict__ h, const float* __restrict__ W,
        const float* __restrict__ sj,
        int* __restrict__ idxsel, float* __restrict__ sjsel,
        float* __restrict__ sjmax, short* __restrict__ Whsel) {
    int bh = blockIdx.x;
    int b = bh >> 2, hh = bh & 3;
    int t = threadIdx.x, lane = t & 63, w = t >> 6;
    __shared__ float sv[NN];
    __shared__ short WT[32][136];            // WT[d][k] = bf16(W[hh][k][d])
    __shared__ int hist16[16][256];
    __shared__ int binInfo[2];               // [0]=Bsel, [1]=cum_before
    __shared__ int wtot[4];
    __shared__ int wtotg[16], wtote[16], woffg[16], woffe[16];
    __shared__ float wmax[16];
    __shared__ int idxLDS[KSEL];

    for (int e = t; e < 32 * 128; e += 1024) {
        int n = e & 31, k = e >> 5;          // coalesced: consecutive t -> consecutive d
        WT[n][k] = f2bf(W[(size_t)hh * (DIN * HD) + k * HD + n]);
    }

    // coalesced sj load; keys in registers
    const float* s = sj + (size_t)bh * NN;
    int j0 = t * 2;
    float2 xx = *(const float2*)(s + j0);
    sv[j0] = xx.x; sv[j0 + 1] = xx.y;
    unsigned u0 = __builtin_bit_cast(unsigned, xx.x);
    unsigned u1 = __builtin_bit_cast(unsigned, xx.y);
    u0 = (u0 & 0x80000000u) ? ~u0 : (u0 | 0x80000000u);
    u1 = (u1 & 0x80000000u) ? ~u1 : (u1 | 0x80000000u);
    float lmax = fmaxf(xx.x, xx.y);
#pragma unroll
    for (int off = 32; off >= 1; off >>= 1) lmax = fmaxf(lmax, __shfl_xor(lmax, off));
    if (lane == 0) wmax[w] = lmax;
    __syncthreads();
    if (t == 0) {
        float m = wmax[0];
#pragma unroll
        for (int i = 1; i < 16; ++i) m = fmaxf(m, wmax[i]);
        sjmax[bh] = m;
    }

    // radix: 4-pass byte histogram, parallel suffix-scan threshold search
    unsigned prefix = 0;
    int need = KSEL;
#pragma unroll
    for (int shift = 24; shift >= 0; shift -= 8) {
        ((int*)hist16)[t] = 0; ((int*)hist16)[t + 1024] = 0;
        ((int*)hist16)[t + 2048] = 0; ((int*)hist16)[t + 3072] = 0;
        __syncthreads();
        unsigned hmask = (shift < 24) ? (0xFFFFFFFFu << (shift + 8)) : 0u;
        if (((u0 ^ prefix) & hmask) == 0) atomicAdd(&hist16[w][(u0 >> shift) & 255], 1);
        if (((u1 ^ prefix) & hmask) == 0) atomicAdd(&hist16[w][(u1 >> shift) & 255], 1);
        __syncthreads();
        int sc = 0, hv = 0, bb = 0;
        if (t < 256) {                 // waves 0..3
            bb = 255 - t;
            hv = 0;
#pragma unroll
            for (int i = 0; i < 16; ++i) hv += hist16[i][bb];
            sc = hv;
#pragma unroll
            for (int off = 1; off < 64; off <<= 1) {
                int u = __shfl_up(sc, off);
                if (lane >= off) sc += u;
            }
            if (lane == 63) wtot[w] = sc;
        }
        __syncthreads();
        if (t < 256) {
            int woffset = 0;
#pragma unroll
            for (int i = 0; i < 4; ++i) woffset += (i < w) ? wtot[i] : 0;
            int incl = sc + woffset;
            int excl = incl - hv;
            if (incl >= need && excl < need) {   // unique thread
                binInfo[0] = bb;
                binInfo[1] = excl;
            }
        }
        __syncthreads();
        prefix |= ((unsigned)binInfo[0]) << shift;
        need -= binInfo[1];
        __syncthreads();
    }
    unsigned T = prefix;
    int n_gt = KSEL - need;        // count of keys strictly > T

    // ordered compaction (thread t owns j0, j0+1)
    int cg = (u0 > T ? 1 : 0) + (u1 > T ? 1 : 0);
    int ce = (u0 == T ? 1 : 0) + (u1 == T ? 1 : 0);
    int sg = cg, se = ce;
#pragma unroll
    for (int off = 1; off < 64; off <<= 1) {
        int ug = __shfl_up(sg, off), ue = __shfl_up(se, off);
        if (lane >= off) { sg += ug; se += ue; }
    }
    if (lane == 63) { wtotg[w] = sg; wtote[w] = se; }
    __syncthreads();
    if (t == 0) {
        int rg = 0, re = 0;
#pragma unroll
        for (int i = 0; i < 16; ++i) {
            woffg[i] = rg; rg += wtotg[i];
            woffe[i] = re; re += wtote[i];
        }
    }
    __syncthreads();
    int pg = woffg[w] + sg - cg;
    int te = woffe[w] + se - ce;
    {
        unsigned kk[2] = {u0, u1};
#pragma unroll
        for (int r = 0; r < 2; ++r) {
            int j = j0 + r;
            if (kk[r] > T) {
                idxsel[bh * KSEL + pg] = j;
                sjsel[bh * KSEL + pg] = sv[j];
                idxLDS[pg] = j;
                pg++;
            } else if (kk[r] == T) {
                if (te < need) {
                    int pos = n_gt + te;
                    idxsel[bh * KSEL + pos] = j;
                    sjsel[bh * KSEL + pos] = sv[j];
                    idxLDS[pos] = j;
                }
                te++;
            }
        }
    }
    __syncthreads();

    // Phase D: Whsel[bh][d][jj] = bf16( h[idxLDS[jj]] @ W[hh] ), tail zero.
    {
        int mr = lane & 15, quad = lane >> 4;
        int jjp = w * 16 + mr;
        bool valid = jjp < KSEL;
        const float* hrow = h + ((size_t)b * NN + (valid ? idxLDS[jjp] : 0)) * DIN + quad * 8;
        float4v acc0 = {0.f, 0.f, 0.f, 0.f};
        float4v acc1 = {0.f, 0.f, 0.f, 0.f};
#pragma unroll
        for (int ks = 0; ks < 4; ++ks) {
            short8 afr;
            if (valid) {
                float4 xa = *(const float4*)(hrow + ks * 32);
                float4 xb = *(const float4*)(hrow + ks * 32 + 4);
                afr[0] = f2bf(xa.x); afr[1] = f2bf(xa.y); afr[2] = f2bf(xa.z); afr[3] = f2bf(xa.w);
                afr[4] = f2bf(xb.x); afr[5] = f2bf(xb.y); afr[6] = f2bf(xb.z); afr[7] = f2bf(xb.w);
            } else {
                afr = (short8){0, 0, 0, 0, 0, 0, 0, 0};
            }
            short8 b0 = *(const short8*)&WT[mr][ks * 32 + quad * 8];
            short8 b1 = *(const short8*)&WT[16 + mr][ks * 32 + quad * 8];
            acc0 = __builtin_amdgcn_mfma_f32_16x16x32_bf16(afr, b0, acc0, 0, 0, 0);
            acc1 = __builtin_amdgcn_mfma_f32_16x16x32_bf16(afr, b1, acc1, 0, 0, 0);
        }
        short4v o0, o1;
#pragma unroll
        for (int r = 0; r < 4; ++r) { o0[r] = f2bf(acc0[r]); o1[r] = f2bf(acc1[r]); }
        size_t base = (size_t)bh * HD * KPAD;
        int jjs = w * 16 + quad * 4;
        *(short4v*)&Whsel[base + (size_t)mr * KPAD + jjs] = o0;
        *(short4v*)&Whsel[base + (size_t)(16 + mr) * KPAD + jjs] = o1;
    }
}

// ---------------------------------------------------------------------------
// K3 v4: OCCUPANCY restructure. Block = 512 threads / 8 waves = (head hh,
// half g) pairs; grid 512. Same 2-row double-buffered gload_lds pipeline as
// r4 (verified correct), but within each stage wave g processes row g, so
// all 8 waves are active every stage. Epilogue: wave g computes output half
// ni=g (bfr halves to 8 regs). LDS ~75 KB -> 2 blocks/CU x 8 waves =
// 16 waves/CU (was 8): 2x latency hiding for the gather chains.
__global__ __launch_bounds__(512) void attn2_kernel(
        const float* __restrict__ adj, const float* __restrict__ si,
        const int* __restrict__ idxsel, const float* __restrict__ sjsel,
        const float* __restrict__ sjmax, const short* __restrict__ Whsel,
        float* __restrict__ out) {
    int b = blockIdx.x >> 7;        // 4
    int tile = blockIdx.x & 127;    // 128 tiles of 16 rows
    __shared__ float adjbuf[2][2][NN];       // 32 KB double buffer, 2 rows/stage
    __shared__ short PSb[HH][16][KST];       // 33 KB
    __shared__ int   idxS[HH][KPAD];         // 4 KB
    __shared__ float sjS[HH][KPAD];          // 4 KB
    __shared__ float invZS[HH][16];
    __shared__ float smaxS[HH];
    int t = threadIdx.x, w8 = t >> 6, lane = t & 63;
    int hh = w8 >> 1, g = w8 & 1;            // head, half
    int mr = lane & 15, quad = lane >> 4;

    int i0 = tile * 16;
    const char* adjb = (const char*)(adj + (size_t)b * NN * NN + (size_t)i0 * NN);

    // ---- prologue: tables + B-fragments + si ----
    for (int e = t; e < HH * KPAD; e += 512) {
        int h2 = e >> 8, jj = e & 255;
        bool v = jj < KSEL;
        idxS[h2][jj] = v ? idxsel[(b * HH + h2) * KSEL + jj] : 0;
        sjS[h2][jj]  = v ? sjsel[(b * HH + h2) * KSEL + jj] : -1e30f;
    }
    if (t < HH) smaxS[t] = sjmax[b * HH + t];

    short8 bfr[8];                           // only ni = g half
    {
        const short* wp = Whsel + (size_t)((b * HH + hh) * HD) * KPAD;
#pragma unroll
        for (int ks = 0; ks < 8; ++ks)
            bfr[ks] = *(const short8*)(wp + (size_t)(g * 16 + mr) * KPAD + ks * 32 + quad * 8);
    }
    int bh = b * HH + hh;
    // lane l (<8) holds si of row i0 + 2*l + g (this wave's rows in stage order)
    float sivAll = (lane < 8) ? si[(size_t)bh * NN + i0 + 2 * lane + g] : 0.f;

    __syncthreads();   // publishes tables; drains vmcnt to 0 (clean slate)

    // ---- pipeline prologue: stage 0 -> buf0, stage 1 -> buf1 ----
    // per stage (16 KB): wave w8 copies 1 KB at off=w8*1024 in each 8 KB row.
    {
        int lx = lane << 4, off = w8 << 10;
        gload_lds16(adjb + off + lx,              (char*)&adjbuf[0][0][0] + off);
        gload_lds16(adjb + 8192 + off + lx,       (char*)&adjbuf[0][0][0] + 8192 + off);
        gload_lds16(adjb + 16384 + off + lx,      (char*)&adjbuf[1][0][0] + off);
        gload_lds16(adjb + 24576 + off + lx,      (char*)&adjbuf[1][0][0] + 8192 + off);
    }
    asm volatile("s_waitcnt vmcnt(2)" ::: "memory");   // stage-0 done; stage-1 in flight
    __builtin_amdgcn_sched_barrier(0);
    __builtin_amdgcn_s_barrier();

    float smax = smaxS[hh];
    for (int s = 0; s < 8; ++s) {
        int cur = s & 1;
        // issue stage s+1 (buffer cur^1 released by previous barrier)
        if (s >= 1 && s < 7) {
            const char* gs = adjb + (size_t)(s + 1) * 16384;
            char* lb = (char*)&adjbuf[cur ^ 1][0][0];
            int lx = lane << 4, off = w8 << 10;
            gload_lds16(gs + off + lx,        lb + off);
            gload_lds16(gs + 8192 + off + lx, lb + 8192 + off);
        }
        // compute MY row of this stage: global row i0 + 2s + g
        {
            int i_loc = 2 * s + g;
            float siv = __shfl(sivAll, s);
            float m = siv + smax;
            m = (m >= 0.f) ? m : 0.2f * m;
            float z = 0.f;
            short* prow = &PSb[hh][i_loc][0];
#pragma unroll
            for (int k = 0; k < 2; ++k) {
                int jj = k * 128 + lane * 2;
                int ja = idxS[hh][jj], jb = idxS[hh][jj + 1];
                float ava = adjbuf[cur][g][ja], avb = adjbuf[cur][g][jb];
                float ea = siv + sjS[hh][jj];
                float eb = siv + sjS[hh][jj + 1];
                ea = (ea >= 0.f) ? ea : 0.2f * ea;
                eb = (eb >= 0.f) ? eb : 0.2f * eb;
                float ca = __expf(ea - m);
                float cb = __expf(eb - m);
                z += ca + cb;
                short2 p;
                p.x = f2bf(ca * ava);
                p.y = f2bf(cb * avb);
                *(short2*)&prow[jj] = p;
            }
#pragma unroll
            for (int off = 32; off >= 1; off >>= 1) z += __shfl_xor(z, off);
            if (lane == 0) invZS[hh][i_loc] = 1.0f / z;
        }
        if (s < 7) {
            asm volatile("s_waitcnt vmcnt(0)" ::: "memory");   // stage s+1 landed
            __builtin_amdgcn_sched_barrier(0);
            __builtin_amdgcn_s_barrier();
        }
    }
    __syncthreads();   // publish PSb (both waves of each pair) + invZS

    // MFMA: wave (hh,g) computes output half ni=g for all 16 rows
    {
        float4v acc = {0.f, 0.f, 0.f, 0.f};
#pragma unroll
        for (int ks = 0; ks < 8; ++ks) {
            short8 afr = *(const short8*)&PSb[hh][mr][ks * 32 + quad * 8];
            acc = __builtin_amdgcn_mfma_f32_16x16x32_bf16(afr, bfr[ks], acc, 0, 0, 0);
        }
#pragma unroll
        for (int r = 0; r < 4; ++r) {
            int i_loc = quad * 4 + r;
            int d = g * 16 + mr;
            out[((size_t)(b * NN + i0 + i_loc)) * (HH * HD) + hh * HD + d] =
                acc[r] * invZS[hh][i_loc];
        }
    }
}

// ---------------------------------------------------------------------------
extern "C" void kernel_launch(void* const* d_in, const int* in_sizes, int n_in,
                              void* d_out, int out_size, void* d_ws, size_t ws_size,
                              hipStream_t stream) {
    const float* h   = (const float*)d_in[0];   // [B,N,DIN]
    const float* adj = (const float*)d_in[1];   // [B,N,N]
    const float* W   = (const float*)d_in[2];   // [H,DIN,HD]
    const float* a   = (const float*)d_in[3];   // [H,2*HD]
    float* out = (float*)d_out;                 // [B,N,H*HD]

    float* si     = (float*)d_ws;                        // BH*NN f32
    float* sj     = si + (size_t)BH * NN;                // BH*NN
    float* sjsel  = sj + (size_t)BH * NN;                // BH*KSEL
    float* sjmax  = sjsel + (size_t)BH * KSEL;           // BH (pad 16)
    int*   idxsel = (int*)(sjmax + 16);                  // BH*KSEL
    short* Whsel  = (short*)(idxsel + (size_t)BH * KSEL);// BH*HD*KPAD bf16

    s_kernel<<<128, 256, 0, stream>>>(h, W, a, si, sj);
    select_kernel<<<BH, 1024, 0, stream>>>(h, W, sj, idxsel, sjsel, sjmax, Whsel);
    attn2_kernel<<<BB * 128, 512, 0, stream>>>(adj, si, idxsel, sjsel, sjmax, Whsel, out);
}